// Round 1
// baseline (191.956 us; speedup 1.0000x reference)
//
#include <hip/hip_runtime.h>

// DWT2d db4, single fused kernel.
// x: (96, 512, 512) fp32 -> out: (96*4, 256, 256) fp32
// out[bc*4+s][i][j] = sum_{p,q} x[bc][(2i+p)%512][(2j+q)%512] * fH[s][p]*fW[s][q]
// Separable: row pass (along W) -> lo/hi intermediates in LDS -> col pass (along H).

#define TI 16               // output rows per block
#define TJ 64               // output cols per block
#define PR (2*TI + 6)       // 38 patch rows
#define PC (2*TJ + 6)       // 134 patch cols
#define HH 512
#define WW 512

__global__ __launch_bounds__(256)
void dwt2d_db4_kernel(const float* __restrict__ x,
                      const float* __restrict__ dec,
                      float* __restrict__ out) {
    __shared__ float sm_x[PR][PC];     // input patch
    __shared__ float sm_lo[PR][TJ];    // row-pass lo
    __shared__ float sm_hi[PR][TJ];    // row-pass hi

    const int tid = threadIdx.x;
    const int jt  = blockIdx.x;        // 0..3   (W/2 / TJ)
    const int it  = blockIdx.y;        // 0..15  (H/2 / TI)
    const int bc  = blockIdx.z;        // 0..95

    const int rowBase = it * (2 * TI);
    const int colBase = jt * (2 * TJ);

    // Filters (dec[0][k]=lo, dec[1][k]=hi) — uniform address, scalar-cached loads.
    float flo[8], fhi[8];
#pragma unroll
    for (int k = 0; k < 8; ++k) { flo[k] = dec[k]; fhi[k] = dec[8 + k]; }

    const float* xb = x + (size_t)bc * HH * WW;

    // ---- Load patch (circular wrap at the far edge only; single wrap suffices) ----
    for (int idx = tid; idx < PR * PC; idx += 256) {
        int r = idx / PC;
        int c = idx - r * PC;
        int gr = rowBase + r; if (gr >= HH) gr -= HH;
        int gc = colBase + c; if (gc >= WW) gc -= WW;
        sm_x[r][c] = xb[gr * WW + gc];
    }
    __syncthreads();

    // ---- Row pass: lo/hi along W. lanes j-consecutive; sm_x read stride-2 (2-way: free) ----
    for (int idx = tid; idx < PR * TJ; idx += 256) {
        int r = idx >> 6;      // / TJ
        int j = idx & 63;      // % TJ
        float lo = 0.f, hi = 0.f;
#pragma unroll
        for (int q = 0; q < 8; ++q) {
            float v = sm_x[r][2 * j + q];
            lo += v * flo[q];
            hi += v * fhi[q];
        }
        sm_lo[r][j] = lo;
        sm_hi[r][j] = hi;
    }
    __syncthreads();

    // ---- Col pass + store. lanes j-consecutive: conflict-free LDS, coalesced stores ----
    for (int idx = tid; idx < TI * TJ; idx += 256) {
        int i = idx >> 6;
        int j = idx & 63;
        float ll = 0.f, lh = 0.f, hl = 0.f, hh = 0.f;
#pragma unroll
        for (int p = 0; p < 8; ++p) {
            float a = sm_lo[2 * i + p][j];
            float b = sm_hi[2 * i + p][j];
            ll += a * flo[p];
            lh += a * fhi[p];
            hl += b * flo[p];
            hh += b * fhi[p];
        }
        int oi = it * TI + i;
        int oj = jt * TJ + j;
        size_t base = ((size_t)(bc * 4) * 256 + oi) * 256 + oj;
        out[base]               = ll;
        out[base + 1 * 65536]   = lh;
        out[base + 2 * 65536]   = hl;
        out[base + 3 * 65536]   = hh;
    }
}

extern "C" void kernel_launch(void* const* d_in, const int* in_sizes, int n_in,
                              void* d_out, int out_size, void* d_ws, size_t ws_size,
                              hipStream_t stream) {
    const float* x   = (const float*)d_in[0];
    const float* dec = (const float*)d_in[1];
    float* out = (float*)d_out;

    dim3 grid(256 / TJ, 256 / TI, 96);   // (4, 16, 96)
    dim3 block(256);
    dwt2d_db4_kernel<<<grid, block, 0, stream>>>(x, dec, out);
}

// Round 3
// 180.280 us; speedup vs baseline: 1.0648x; 1.0648x over previous
//
#include <hip/hip_runtime.h>

// DWT2d db4, single fused kernel — vectorized (b128 LDS / float4 global).
// x: (96, 512, 512) fp32 -> out: (96*4, 256, 256) fp32
// out[bc*4+s][i][j] = sum_{p,q} x[bc][(2i+p)%512][(2j+q)%512] * fH[s][p]*fW[s][q]

#define TI 16               // output rows per block
#define TJ 64               // output cols per block
#define PR (2*TI + 6)       // 38 patch rows
#define PC 136              // padded patch cols (need 134; row pass reads to col 135)
#define HH 512
#define WW 512

typedef float v4f __attribute__((ext_vector_type(4)));  // native vector for nontemporal

__global__ __launch_bounds__(256)
void dwt2d_db4_kernel(const float* __restrict__ x,
                      const float* __restrict__ dec,
                      float* __restrict__ out) {
    __shared__ __align__(16) float sm_x[PR][PC];    // 20672 B
    __shared__ __align__(16) float sm_lo[PR][TJ];   //  9728 B
    __shared__ __align__(16) float sm_hi[PR][TJ];   //  9728 B

    const int tid = threadIdx.x;
    const int jt  = blockIdx.x;        // 0..3
    const int it  = blockIdx.y;        // 0..15
    const int bc  = blockIdx.z;        // 0..95

    const int rowBase = it * (2 * TI);
    const int colBase = jt * (2 * TJ);

    float flo[8], fhi[8];
#pragma unroll
    for (int k = 0; k < 8; ++k) { flo[k] = dec[k]; fhi[k] = dec[8 + k]; }

    const float* xb = x + (size_t)bc * HH * WW;

    // ---- Patch load: float4 global loads, scalar wrap fallback for tail cols ----
    {
        const int C4 = PC / 4;                       // 34
        for (int idx = tid; idx < PR * C4; idx += 256) {
            int r  = idx / C4;
            int c4 = idx - r * C4;
            int gr = rowBase + r; if (gr >= HH) gr -= HH;
            int gc = colBase + 4 * c4;
            const float* src = xb + gr * WW;
            float4 v;
            if (gc + 3 < WW) {
                v = *(const float4*)(src + gc);
            } else {
                v = make_float4(src[gc & (WW-1)], src[(gc+1) & (WW-1)],
                                src[(gc+2) & (WW-1)], src[(gc+3) & (WW-1)]);
            }
            *(float4*)&sm_x[r][4 * c4] = v;
        }
    }
    __syncthreads();

    // ---- Row pass: thread -> output pair (2t, 2t+1) of row r.
    //      3x ds_read_b128 (lane-consecutive) for 2 outputs; float2 writes. ----
    for (int task = tid; task < PR * (TJ / 2); task += 256) {   // 1216 tasks
        int r = task >> 5;            // / 32
        int t = task & 31;
        const float* xr = &sm_x[r][4 * t];
        float4 v0 = *(const float4*)(xr);
        float4 v1 = *(const float4*)(xr + 4);
        float4 v2 = *(const float4*)(xr + 8);
        float w[12] = { v0.x, v0.y, v0.z, v0.w,
                        v1.x, v1.y, v1.z, v1.w,
                        v2.x, v2.y, v2.z, v2.w };
        float lo0 = 0.f, hi0 = 0.f, lo1 = 0.f, hi1 = 0.f;
#pragma unroll
        for (int q = 0; q < 8; ++q) {
            lo0 += w[q]     * flo[q];
            hi0 += w[q]     * fhi[q];
            lo1 += w[q + 2] * flo[q];
            hi1 += w[q + 2] * fhi[q];
        }
        *(float2*)&sm_lo[r][2 * t] = make_float2(lo0, lo1);
        *(float2*)&sm_hi[r][2 * t] = make_float2(hi0, hi1);
    }
    __syncthreads();

    // ---- Col pass: thread -> 4 consecutive j, all 4 subbands. 16x b128 reads,
    //      v4f nontemporal coalesced stores. Exactly 256 tasks. ----
    {
        int i  = tid >> 4;            // 0..15
        int jb = tid & 15;            // 0..15
        int j0 = 4 * jb;
        float llx=0.f, lly=0.f, llz=0.f, llw=0.f;
        float lhx=0.f, lhy=0.f, lhz=0.f, lhw=0.f;
        float hlx=0.f, hly=0.f, hlz=0.f, hlw=0.f;
        float hhx=0.f, hhy=0.f, hhz=0.f, hhw=0.f;
#pragma unroll
        for (int p = 0; p < 8; ++p) {
            float4 a = *(const float4*)&sm_lo[2 * i + p][j0];
            float4 b = *(const float4*)&sm_hi[2 * i + p][j0];
            float cl = flo[p], ch = fhi[p];
            llx += a.x * cl; lly += a.y * cl; llz += a.z * cl; llw += a.w * cl;
            lhx += a.x * ch; lhy += a.y * ch; lhz += a.z * ch; lhw += a.w * ch;
            hlx += b.x * cl; hly += b.y * cl; hlz += b.z * cl; hlw += b.w * cl;
            hhx += b.x * ch; hhy += b.y * ch; hhz += b.z * ch; hhw += b.w * ch;
        }
        int oi = it * TI + i;
        int oj = jt * TJ + j0;
        size_t base = ((size_t)(bc * 4) * 256 + oi) * 256 + oj;
        v4f ll = { llx, lly, llz, llw };
        v4f lh = { lhx, lhy, lhz, lhw };
        v4f hl = { hlx, hly, hlz, hlw };
        v4f hh = { hhx, hhy, hhz, hhw };
        __builtin_nontemporal_store(ll, (v4f*)&out[base]);
        __builtin_nontemporal_store(lh, (v4f*)&out[base + 1 * 65536]);
        __builtin_nontemporal_store(hl, (v4f*)&out[base + 2 * 65536]);
        __builtin_nontemporal_store(hh, (v4f*)&out[base + 3 * 65536]);
    }
}

extern "C" void kernel_launch(void* const* d_in, const int* in_sizes, int n_in,
                              void* d_out, int out_size, void* d_ws, size_t ws_size,
                              hipStream_t stream) {
    const float* x   = (const float*)d_in[0];
    const float* dec = (const float*)d_in[1];
    float* out = (float*)d_out;

    dim3 grid(256 / TJ, 256 / TI, 96);   // (4, 16, 96)
    dim3 block(256);
    dwt2d_db4_kernel<<<grid, block, 0, stream>>>(x, dec, out);
}